// Round 17
// baseline (1472.325 us; speedup 1.0000x reference)
//
#include <hip/hip_runtime.h>
#include <hip/hip_bf16.h>
#include <math.h>

#define NROWS 8192
#define DFEAT 2048
#define KSEL  64
#define CHK   2048   // symmetric pair chunk

typedef unsigned long long u64;
typedef __attribute__((ext_vector_type(8))) short bf16x8;
typedef __attribute__((ext_vector_type(4))) float f32x4;

__device__ __forceinline__ u64 umax64(u64 a, u64 b) { return a > b ? a : b; }

__device__ __forceinline__ void split2(float v, ushort& h, ushort& l) {
  __hip_bfloat16 bh = __float2bfloat16(v);
  float r = v - __bfloat162float(bh);
  __hip_bfloat16 bl = __float2bfloat16(r);
  h = *(ushort*)&bh; l = *(ushort*)&bl;
}

__device__ __forceinline__ u64 mkkey_vi(float v, int i) {
  unsigned u = __float_as_uint(v);
  u = ((int)u < 0) ? ~u : (u | 0x80000000u);
  return ((u64)u << 32) | (u64)(0xFFFFFFFFu - (unsigned)i);
}

// ---------------- K0: 3-way bf16 split of F (exact to 2^-27) ----------------
__global__ __launch_bounds__(256) void k_split(const float* __restrict__ F, ushort* __restrict__ H,
                                               ushort* __restrict__ M, ushort* __restrict__ L) {
  const size_t i0 = ((size_t)blockIdx.x * 256 + threadIdx.x) * 4;
  float4 x = *(const float4*)(F + i0);
  float xs[4] = {x.x, x.y, x.z, x.w};
  ushort h[4], m[4], l[4];
#pragma unroll
  for (int c = 0; c < 4; ++c) {
    float v = xs[c];
    __hip_bfloat16 bh = __float2bfloat16(v);
    float r1 = v - __bfloat162float(bh);
    __hip_bfloat16 bm = __float2bfloat16(r1);
    float r2 = r1 - __bfloat162float(bm);
    __hip_bfloat16 bl = __float2bfloat16(r2);
    h[c] = *(ushort*)&bh; m[c] = *(ushort*)&bm; l[c] = *(ushort*)&bl;
  }
  ushort4 vh = {h[0], h[1], h[2], h[3]};
  ushort4 vm = {m[0], m[1], m[2], m[3]};
  ushort4 vl = {l[0], l[1], l[2], l[3]};
  *(ushort4*)(H + i0) = vh;
  *(ushort4*)(M + i0) = vm;
  *(ushort4*)(L + i0) = vl;
}

// ---------------- K1x: batched sim tiles (bf16x6, swizzled LDS) — proven R13 kernel ----------------
// Per-z table entry e: ci | cj<<4 | bufA<<8 | bufB<<12 | diag<<16.
__global__ __launch_bounds__(256) void k_sim_batch(
    const ushort* __restrict__ FH, const ushort* __restrict__ FM, const ushort* __restrict__ FL,
    float* __restrict__ BUFS, int e0, int e1, int e2, int e3, int e4, int e5) {
  __shared__ ushort lds[6 * 4096];
  const int z = blockIdx.z;
  const int e = (z == 0) ? e0 : ((z == 1) ? e1 : ((z == 2) ? e2 : ((z == 3) ? e3 : ((z == 4) ? e4 : e5))));
  const int ci = e & 15, cj = (e >> 4) & 15;
  const int bA = (e >> 8) & 15, bB = (e >> 12) & 15;
  const int diag = (e >> 16) & 1;
  const int bj = blockIdx.x;
  const int bm = blockIdx.y;
  if (diag && bm > bj) return;
  const size_t TSZ = (size_t)CHK * CHK;
  float* TILE = BUFS + (size_t)bA * TSZ;
  float* TILT = BUFS + (size_t)bB * TSZ;
  const int t = threadIdx.x;
  const int w = t >> 6, l = t & 63;
  const int arow0 = ci * CHK + bm * 128;
  const int brow0 = cj * CHK + bj * 128;
  const int segr = l >> 2;
  const int segq_s = (l & 3) ^ ((l >> 3) & 3);
  const int fl15 = l & 15, fq = l >> 4;
  const int kswz = (fq ^ ((fl15 >> 1) & 3)) * 8;
  const int wr = w >> 1, wc = w & 1;
  const int mb = wr * 64, nb = wc * 64;

  f32x4 acc[4][4];
#pragma unroll
  for (int i = 0; i < 4; ++i)
#pragma unroll
    for (int j = 0; j < 4; ++j) acc[i][j] = (f32x4){0.f, 0.f, 0.f, 0.f};

  for (int k0 = 0; k0 < DFEAT; k0 += 32) {
    __syncthreads();
#pragma unroll
    for (int c = 0; c < 12; ++c) {
      const int cidx = w * 12 + c;
      const int tt = cidx >> 3;
      const int p = cidx & 7;
      const int rowbase = (tt < 3) ? arow0 : brow0;
      const int sp = (tt < 3) ? tt : (tt - 3);
      const ushort* sel = (sp == 0) ? FH : ((sp == 1) ? FM : FL);
      const ushort* g = sel + (size_t)(rowbase + p * 16 + segr) * DFEAT + (k0 + segq_s * 8);
      __builtin_amdgcn_global_load_lds((const __attribute__((address_space(1))) unsigned int*)g,
                                       (__attribute__((address_space(3))) unsigned int*)&lds[tt * 4096 + p * 512],
                                       16, 0, 0);
    }
    __syncthreads();

    bf16x8 af[3][4];
    bf16x8 bg[3][4];
#pragma unroll
    for (int i = 0; i < 3; ++i)
#pragma unroll
      for (int fm = 0; fm < 4; ++fm)
        af[i][fm] = *(const bf16x8*)&lds[i * 4096 + (mb + fm * 16 + fl15) * 32 + kswz];
#pragma unroll
    for (int j = 0; j < 3; ++j)
#pragma unroll
      for (int fn = 0; fn < 4; ++fn)
        bg[j][fn] = *(const bf16x8*)&lds[(3 + j) * 4096 + (nb + fn * 16 + fl15) * 32 + kswz];

#pragma unroll
    for (int fm = 0; fm < 4; ++fm)
#pragma unroll
      for (int fn = 0; fn < 4; ++fn) {
        f32x4 a = acc[fm][fn];
        a = __builtin_amdgcn_mfma_f32_16x16x32_bf16(af[0][fm], bg[0][fn], a, 0, 0, 0);
        a = __builtin_amdgcn_mfma_f32_16x16x32_bf16(af[1][fm], bg[0][fn], a, 0, 0, 0);
        a = __builtin_amdgcn_mfma_f32_16x16x32_bf16(af[0][fm], bg[1][fn], a, 0, 0, 0);
        a = __builtin_amdgcn_mfma_f32_16x16x32_bf16(af[2][fm], bg[0][fn], a, 0, 0, 0);
        a = __builtin_amdgcn_mfma_f32_16x16x32_bf16(af[0][fm], bg[2][fn], a, 0, 0, 0);
        a = __builtin_amdgcn_mfma_f32_16x16x32_bf16(af[1][fm], bg[1][fn], a, 0, 0, 0);
        acc[fm][fn] = a;
      }
  }

  const bool doT = !(diag && bm == bj);
#pragma unroll
  for (int fm = 0; fm < 4; ++fm) {
    const int lm = bm * 128 + mb + fm * 16 + fq * 4;
#pragma unroll
    for (int fn = 0; fn < 4; ++fn) {
      const int col = bj * 128 + nb + fn * 16 + fl15;
#pragma unroll
      for (int r = 0; r < 4; ++r)
        TILE[(size_t)(lm + r) * CHK + col] = acc[fm][fn][r];
      if (doT) {
        float4 v = make_float4(acc[fm][fn][0], acc[fm][fn][1], acc[fm][fn][2], acc[fm][fn][3]);
        *(float4*)(TILT + (size_t)col * CHK + lm) = v;
      }
    }
  }
}

// ---------------- K1: chunked row-panel sim (small-ws fallback; clean proven form) ----------------
__global__ __launch_bounds__(256) void k_simgemm_mfma(
    const ushort* __restrict__ FH, const ushort* __restrict__ FM, const ushort* __restrict__ FL,
    float* __restrict__ C, int row0) {
  __shared__ ushort lds[6 * 4096];
  const int bj = blockIdx.x;
  const int bm = blockIdx.y;
  const int t = threadIdx.x;
  const int w = t >> 6, l = t & 63;
  const int arow0 = row0 + bm * 128;
  const int brow0 = bj * 128;
  const int segr = l >> 2;
  const int segq = l & 3;
  const int fl15 = l & 15, fq = l >> 4;
  const int wr = w >> 1, wc = w & 1;
  const int mb = wr * 64, nb = wc * 64;

  f32x4 acc[4][4];
#pragma unroll
  for (int i = 0; i < 4; ++i)
#pragma unroll
    for (int j = 0; j < 4; ++j) acc[i][j] = (f32x4){0.f, 0.f, 0.f, 0.f};

  for (int k0 = 0; k0 < DFEAT; k0 += 32) {
    __syncthreads();
#pragma unroll
    for (int c = 0; c < 12; ++c) {
      const int cc = w * 12 + c;
      const int tt = cc >> 3;
      const int p = cc & 7;
      const int rowbase = (tt < 3) ? arow0 : brow0;
      const int sp = (tt < 3) ? tt : (tt - 3);
      const ushort* sel = (sp == 0) ? FH : ((sp == 1) ? FM : FL);
      const ushort* g = sel + (size_t)(rowbase + p * 16 + segr) * DFEAT + (k0 + segq * 8);
      __builtin_amdgcn_global_load_lds((const __attribute__((address_space(1))) unsigned int*)g,
                                       (__attribute__((address_space(3))) unsigned int*)&lds[tt * 4096 + p * 512],
                                       16, 0, 0);
    }
    __syncthreads();

    bf16x8 af[3][4];
    bf16x8 bg[3][4];
    const int kcol = fq * 8;
#pragma unroll
    for (int i = 0; i < 3; ++i)
#pragma unroll
      for (int fm = 0; fm < 4; ++fm)
        af[i][fm] = *(const bf16x8*)&lds[i * 4096 + (mb + fm * 16 + fl15) * 32 + kcol];
#pragma unroll
    for (int j = 0; j < 3; ++j)
#pragma unroll
      for (int fn = 0; fn < 4; ++fn)
        bg[j][fn] = *(const bf16x8*)&lds[(3 + j) * 4096 + (nb + fn * 16 + fl15) * 32 + kcol];

#pragma unroll
    for (int fm = 0; fm < 4; ++fm)
#pragma unroll
      for (int fn = 0; fn < 4; ++fn) {
        f32x4 a = acc[fm][fn];
        a = __builtin_amdgcn_mfma_f32_16x16x32_bf16(af[0][fm], bg[0][fn], a, 0, 0, 0);
        a = __builtin_amdgcn_mfma_f32_16x16x32_bf16(af[1][fm], bg[0][fn], a, 0, 0, 0);
        a = __builtin_amdgcn_mfma_f32_16x16x32_bf16(af[0][fm], bg[1][fn], a, 0, 0, 0);
        a = __builtin_amdgcn_mfma_f32_16x16x32_bf16(af[2][fm], bg[0][fn], a, 0, 0, 0);
        a = __builtin_amdgcn_mfma_f32_16x16x32_bf16(af[0][fm], bg[2][fn], a, 0, 0, 0);
        a = __builtin_amdgcn_mfma_f32_16x16x32_bf16(af[1][fm], bg[1][fn], a, 0, 0, 0);
        acc[fm][fn] = a;
      }
  }

#pragma unroll
  for (int fm = 0; fm < 4; ++fm) {
    const int lm = bm * 128 + mb + fm * 16 + fq * 4;
#pragma unroll
    for (int fn = 0; fn < 4; ++fn) {
      const int col = bj * 128 + nb + fn * 16 + fl15;
#pragma unroll
      for (int r = 0; r < 4; ++r)
        C[(size_t)(lm + r) * NROWS + col] = acc[fm][fn][r];
    }
  }
}

// ---------------- K1b: generic bf16x3 MFMA GEMM: C = A . B^T (swizzled LDS) ----------------
__global__ __launch_bounds__(256) void k_gemm3(const ushort* __restrict__ AH, const ushort* __restrict__ AL,
                                               const ushort* __restrict__ BH, const ushort* __restrict__ BL,
                                               float* __restrict__ C, int K, int N) {
  __shared__ ushort lds[4 * 4096];
  const int bj = blockIdx.x, bm = blockIdx.y;
  const int t = threadIdx.x;
  const int w = t >> 6, l = t & 63;
  const int segr = l >> 2;
  const int segq_s = (l & 3) ^ ((l >> 3) & 3);
  const int fl15 = l & 15, fq = l >> 4;
  const int kswz = (fq ^ ((fl15 >> 1) & 3)) * 8;
  const int wr = w >> 1, wc = w & 1;
  const int mb = wr * 64, nb = wc * 64;

  f32x4 acc[4][4];
#pragma unroll
  for (int i = 0; i < 4; ++i)
#pragma unroll
    for (int j = 0; j < 4; ++j) acc[i][j] = (f32x4){0.f, 0.f, 0.f, 0.f};

  for (int k0 = 0; k0 < K; k0 += 32) {
    __syncthreads();
#pragma unroll
    for (int c = 0; c < 8; ++c) {
      const int s = w * 8 + c;
      const int tt = s >> 3;
      const int p = s & 7;
      const int rowbase = (tt < 2) ? (bm * 128) : (bj * 128);
      const ushort* sel = (tt == 0) ? AH : ((tt == 1) ? AL : ((tt == 2) ? BH : BL));
      const ushort* g = sel + (size_t)(rowbase + p * 16 + segr) * K + (k0 + segq_s * 8);
      __builtin_amdgcn_global_load_lds((const __attribute__((address_space(1))) unsigned int*)g,
                                       (__attribute__((address_space(3))) unsigned int*)&lds[s * 512],
                                       16, 0, 0);
    }
    __syncthreads();

    bf16x8 af[2][4];
    bf16x8 bg[2][4];
#pragma unroll
    for (int i = 0; i < 2; ++i)
#pragma unroll
      for (int fm = 0; fm < 4; ++fm)
        af[i][fm] = *(const bf16x8*)&lds[i * 4096 + (mb + fm * 16 + fl15) * 32 + kswz];
#pragma unroll
    for (int j = 0; j < 2; ++j)
#pragma unroll
      for (int fn = 0; fn < 4; ++fn)
        bg[j][fn] = *(const bf16x8*)&lds[(2 + j) * 4096 + (nb + fn * 16 + fl15) * 32 + kswz];

#pragma unroll
    for (int fm = 0; fm < 4; ++fm)
#pragma unroll
      for (int fn = 0; fn < 4; ++fn) {
        f32x4 a = acc[fm][fn];
        a = __builtin_amdgcn_mfma_f32_16x16x32_bf16(af[0][fm], bg[0][fn], a, 0, 0, 0);
        a = __builtin_amdgcn_mfma_f32_16x16x32_bf16(af[0][fm], bg[1][fn], a, 0, 0, 0);
        a = __builtin_amdgcn_mfma_f32_16x16x32_bf16(af[1][fm], bg[0][fn], a, 0, 0, 0);
        acc[fm][fn] = a;
      }
  }

#pragma unroll
  for (int fm = 0; fm < 4; ++fm) {
    const int row = bm * 128 + mb + fm * 16 + fq * 4;
#pragma unroll
    for (int fn = 0; fn < 4; ++fn) {
      const int col = bj * 128 + nb + fn * 16 + fl15;
#pragma unroll
      for (int r = 0; r < 4; ++r)
        C[(size_t)(row + r) * N + col] = acc[fm][fn][r];
    }
  }
}

// ---------------- K2i: init running top-k ----------------
__global__ __launch_bounds__(256) void k_init_topk(float* __restrict__ topv, int* __restrict__ topi) {
  const int i = blockIdx.x * 256 + threadIdx.x;
  topv[i] = -INFINITY;
  topi[i] = 0;
}

// ---------------- K2u2: merged update — TWO 2048-col sources + old 64 -> new top-64 ----------------
__global__ __launch_bounds__(256) void k_topk_upd2(const float* __restrict__ bufbase,
                                                   int a0, int a1, int a2, int a3,
                                                   int ca0, int ca1, int ca2, int ca3,
                                                   int b0, int b1, int b2, int b3,
                                                   int cb0, int cb1, int cb2, int cb3,
                                                   float* __restrict__ topv, int* __restrict__ topi) {
  __shared__ unsigned cnt[64];
  __shared__ unsigned nsel;
  __shared__ u64 selbuf[64];
  const int t = threadIdx.x;
  const int y = blockIdx.y;
  const int bA = (y == 0) ? a0 : ((y == 1) ? a1 : ((y == 2) ? a2 : a3));
  const int cA = (y == 0) ? ca0 : ((y == 1) ? ca1 : ((y == 2) ? ca2 : ca3));
  const int bB = (y == 0) ? b0 : ((y == 1) ? b1 : ((y == 2) ? b2 : b3));
  const int cB = (y == 0) ? cb0 : ((y == 1) ? cb1 : ((y == 2) ? cb2 : cb3));
  const size_t TSZ = (size_t)CHK * CHK;
  const int row = y * CHK + blockIdx.x;
  const float* srcA = bufbase + (size_t)bA * TSZ + (size_t)blockIdx.x * CHK;
  const float* srcB = bufbase + (size_t)bB * TSZ + (size_t)blockIdx.x * CHK;

  if (t < 64) cnt[t] = 0;
  if (t == 0) nsel = 0;

  u64 k[17];
  int nk = 16;
#pragma unroll
  for (int q = 0; q < 8; ++q) {
    k[q] = mkkey_vi(srcA[t + 256 * q], cA * CHK + t + 256 * q);
    k[8 + q] = mkkey_vi(srcB[t + 256 * q], cB * CHK + t + 256 * q);
  }
  k[16] = 0;
  if (t < 64) {
    k[16] = mkkey_vi(topv[(size_t)row * KSEL + t], topi[(size_t)row * KSEL + t]);
    nk = 17;
  }
  __syncthreads();

  u64 T64 = 0;
  for (int bit = 63; bit >= 0; --bit) {
    const u64 cand = T64 | (1ull << bit);
    unsigned c = 0;
#pragma unroll
    for (int q = 0; q < 17; ++q) c += (q < nk && k[q] >= cand) ? 1u : 0u;
#pragma unroll
    for (int s = 32; s > 0; s >>= 1) c += __shfl_down(c, s);
    if ((t & 63) == 0) atomicAdd(&cnt[bit], c);
    __syncthreads();
    const unsigned cb = cnt[bit];
    if (cb >= 64) T64 = cand;
    if (cb == 64) break;
  }

#pragma unroll
  for (int q = 0; q < 17; ++q) {
    if (q < nk && k[q] >= T64) {
      unsigned p = atomicAdd(&nsel, 1u);
      if (p < 64) selbuf[p] = k[q];
    }
  }
  __syncthreads();

  if (t < 64) {
    u64 key = selbuf[t];
#pragma unroll
    for (int kk = 2; kk <= 64; kk <<= 1) {
#pragma unroll
      for (int j = kk >> 1; j > 0; j >>= 1) {
        u64 other = __shfl_xor(key, j);
        const bool dirDesc = ((t & kk) == 0);
        const bool upper = ((t & j) != 0);
        u64 mx = umax64(key, other);
        u64 mn = (key < other) ? key : other;
        key = (dirDesc ^ upper) ? mx : mn;
      }
    }
    const unsigned ui = (unsigned)(key >> 32);
    const float v = __uint_as_float((ui & 0x80000000u) ? (ui ^ 0x80000000u) : ~ui);
    const int idx = (int)(0xFFFFFFFFu - (unsigned)(key & 0xFFFFFFFFull));
    topv[(size_t)row * KSEL + t] = v;
    topi[(size_t)row * KSEL + t] = idx;
  }
}

// shared body: merge one 2048-col source + old 64 -> new top-64 (4-buffer path)
__device__ __forceinline__ void topk_merge_body(const float* src, int row, int colbase,
                                                float* topv, int* topi,
                                                unsigned* cnt, unsigned* nselp, u64* selbuf) {
  const int t = threadIdx.x;
  if (t < 64) cnt[t] = 0;
  if (t == 0) *nselp = 0;

  u64 k[9];
  int nk = 8;
#pragma unroll
  for (int q = 0; q < 8; ++q) {
    float v = src[t + 256 * q];
    k[q] = mkkey_vi(v, colbase + t + 256 * q);
  }
  k[8] = 0;
  if (t < 64) {
    k[8] = mkkey_vi(topv[(size_t)row * KSEL + t], topi[(size_t)row * KSEL + t]);
    nk = 9;
  }
  __syncthreads();

  u64 T64 = 0;
  for (int bit = 63; bit >= 0; --bit) {
    const u64 cand = T64 | (1ull << bit);
    unsigned c = 0;
#pragma unroll
    for (int q = 0; q < 9; ++q) c += (q < nk && k[q] >= cand) ? 1u : 0u;
#pragma unroll
    for (int s = 32; s > 0; s >>= 1) c += __shfl_down(c, s);
    if ((t & 63) == 0) atomicAdd(&cnt[bit], c);
    __syncthreads();
    const unsigned cb = cnt[bit];
    if (cb >= 64) T64 = cand;
    if (cb == 64) break;
  }

#pragma unroll
  for (int q = 0; q < 9; ++q) {
    if (q < nk && k[q] >= T64) {
      unsigned p = atomicAdd(nselp, 1u);
      if (p < 64) selbuf[p] = k[q];
    }
  }
  __syncthreads();

  if (t < 64) {
    u64 key = selbuf[t];
#pragma unroll
    for (int kk = 2; kk <= 64; kk <<= 1) {
#pragma unroll
      for (int j = kk >> 1; j > 0; j >>= 1) {
        u64 other = __shfl_xor(key, j);
        const bool dirDesc = ((t & kk) == 0);
        const bool upper = ((t & j) != 0);
        u64 mx = umax64(key, other);
        u64 mn = (key < other) ? key : other;
        key = (dirDesc ^ upper) ? mx : mn;
      }
    }
    const unsigned ui = (unsigned)(key >> 32);
    const float v = __uint_as_float((ui & 0x80000000u) ? (ui ^ 0x80000000u) : ~ui);
    const int idx = (int)(0xFFFFFFFFu - (unsigned)(key & 0xFFFFFFFFull));
    topv[(size_t)row * KSEL + t] = v;
    topi[(size_t)row * KSEL + t] = idx;
  }
}

// ---------------- K2u4: single-source update (4-buffer path) ----------------
__global__ __launch_bounds__(256) void k_topk_upd4(const float* __restrict__ bufbase,
                                                   int b0, int b1, int b2, int b3,
                                                   int c0, int c1, int c2, int c3,
                                                   float* __restrict__ topv, int* __restrict__ topi) {
  __shared__ unsigned cnt[64];
  __shared__ unsigned nsel;
  __shared__ u64 selbuf[64];
  const int y = blockIdx.y;
  const int bi = (y == 0) ? b0 : ((y == 1) ? b1 : ((y == 2) ? b2 : b3));
  const int cc = (y == 0) ? c0 : ((y == 1) ? c1 : ((y == 2) ? c2 : c3));
  const size_t TSZ = (size_t)CHK * CHK;
  const float* src = bufbase + (size_t)bi * TSZ + (size_t)blockIdx.x * CHK;
  topk_merge_body(src, y * CHK + blockIdx.x, cc * CHK, topv, topi, cnt, &nsel, selbuf);
}

// ---------------- K2e: exps from final top-10 ----------------
__global__ __launch_bounds__(256) void k_exps(const float* __restrict__ topv, float* __restrict__ exps) {
  const int r = blockIdx.x * 256 + threadIdx.x;
  float s = 0.f;
#pragma unroll
  for (int q = 0; q < 10; ++q) s += topv[(size_t)r * KSEL + q];
  exps[r] = expf(s / 40.0f);
}

// ---------------- K2: full-row top-64 (small-ws fallback) ----------------
__global__ __launch_bounds__(256) void k_topk(const float* __restrict__ simc,
                                              float* __restrict__ topv, int* __restrict__ topi,
                                              float* __restrict__ exps, int row0) {
  __shared__ float vals[NROWS];
  __shared__ u64 wmax[4];
  __shared__ float outv[KSEL];
  __shared__ int outi[KSEL];
  const int row = row0 + blockIdx.x;
  const int t = threadIdx.x;
  const float* src = simc + (size_t)blockIdx.x * NROWS;
  for (int i = t; i < NROWS; i += 256) vals[i] = src[i];
  __syncthreads();

  u64 lk = 0;
#pragma unroll
  for (int m = 0; m < 32; ++m) {
    int i = t + 256 * m;
    lk = umax64(lk, mkkey_vi(vals[i], i));
  }

  const int lane = t & 63, wv = t >> 6;
  for (int it = 0; it < KSEL; ++it) {
    u64 wk = lk;
#pragma unroll
    for (int s = 32; s > 0; s >>= 1) {
      u64 o = __shfl_xor(wk, s);
      wk = umax64(wk, o);
    }
    if (lane == 0) wmax[wv] = wk;
    __syncthreads();
    u64 g = umax64(umax64(wmax[0], wmax[1]), umax64(wmax[2], wmax[3]));
    const unsigned ui = (unsigned)(g >> 32);
    const float v = __uint_as_float((ui & 0x80000000u) ? (ui ^ 0x80000000u) : ~ui);
    const int idx = (int)(0xFFFFFFFFu - (unsigned)(g & 0xFFFFFFFFull));
    if (t == 0) { outv[it] = v; outi[it] = idx; }
    if (t == (idx & 255)) {
      vals[idx] = -INFINITY;
      u64 nl = 0;
#pragma unroll
      for (int m = 0; m < 32; ++m) {
        int i = t + 256 * m;
        nl = umax64(nl, mkkey_vi(vals[i], i));
      }
      lk = nl;
    }
    __syncthreads();
  }
  if (t < KSEL) {
    topv[(size_t)row * KSEL + t] = outv[t];
    topi[(size_t)row * KSEL + t] = outi[t];
  }
  if (t == 0) {
    float s = 0.f;
#pragma unroll
    for (int q = 0; q < 10; ++q) s += outv[q];
    exps[row] = expf(s / 40.0f);
  }
}

// ---------------- K3: adjacency build + row softmax ----------------
__global__ __launch_bounds__(256) void k_adj(const int* __restrict__ indexes,
                                             const float* __restrict__ topv, const int* __restrict__ topi,
                                             const float* __restrict__ exps, float* __restrict__ adj) {
  __shared__ int nbr[64];
  __shared__ int neigh[64][10];
  __shared__ float tv[64][10];
  __shared__ float adjL[64][64];
  const int b = blockIdx.x;
  const int t = threadIdx.x;
  const int idx = indexes[b];
  if (t < 64) nbr[t] = topi[(size_t)idx * KSEL + t];
  __syncthreads();
  for (int p = t; p < 640; p += 256) {
    const int r = p / 10, q = p - r * 10;
    const int m = nbr[r];
    const int c = topi[(size_t)m * KSEL + q];
    neigh[r][q] = c;
    tv[r][q] = topv[(size_t)m * KSEL + q] * exps[c];
  }
  __syncthreads();
  for (int p = t; p < 4096; p += 256) {
    const int i = p >> 6, j = p & 63;
    float s = 0.f;
#pragma unroll
    for (int q = 0; q < 10; ++q) {
      const int c = neigh[i][q];
      float add = 0.f;
      for (int s2 = 0; s2 < 10; ++s2) {
        if (neigh[j][s2] == c) { add = (tv[j][s2] > 0.f) ? tv[i][q] : 0.f; break; }
      }
      s += add;
    }
    adjL[i][j] = s;
  }
  __syncthreads();
  const int wv = t >> 6, lane = t & 63;
  for (int i = wv * 16; i < wv * 16 + 16; ++i) {
    float v = adjL[i][lane];
    float mx = v;
#pragma unroll
    for (int s = 32; s > 0; s >>= 1) mx = fmaxf(mx, __shfl_xor(mx, s));
    float e = expf(v - mx);
    float sum = e;
#pragma unroll
    for (int s = 32; s > 0; s >>= 1) sum += __shfl_xor(sum, s);
    adj[((size_t)b * 64 + i) * 64 + lane] = e / sum;
  }
}

// ---------------- K4: xs splits ----------------
__global__ __launch_bounds__(256) void k_xs_split(const int* __restrict__ indexes, const int* __restrict__ topi,
                                                  const float* __restrict__ F,
                                                  ushort* __restrict__ XH, ushort* __restrict__ XL) {
  const int b = blockIdx.y, r = blockIdx.x;
  const int t = threadIdx.x;
  const int idx = indexes[b];
  const int m  = topi[(size_t)idx * KSEL + r];
  const int m0 = topi[(size_t)idx * KSEL + 0];
  const float4* pa = (const float4*)(F + (size_t)m * DFEAT);
  const float4* pb = (const float4*)(F + (size_t)m0 * DFEAT);
  const size_t rowoff = ((size_t)b * 64 + r) * DFEAT;
#pragma unroll
  for (int it = 0; it < 2; ++it) {
    const int i = t + it * 256;
    float4 a = pa[i], c = pb[i];
    float d[4] = {a.x - c.x, a.y - c.y, a.z - c.z, a.w - c.w};
    ushort h[4], l[4];
#pragma unroll
    for (int q = 0; q < 4; ++q) split2(d[q], h[q], l[q]);
    ushort4 vh = {h[0], h[1], h[2], h[3]};
    ushort4 vl = {l[0], l[1], l[2], l[3]};
    *(ushort4*)(XH + rowoff + i * 4) = vh;
    *(ushort4*)(XL + rowoff + i * 4) = vl;
  }
}

// ---------------- K5: weight pre-split, transposed + combined ----------------
__global__ __launch_bounds__(256) void k_wsplitT(const float* __restrict__ W,
                                                 ushort* __restrict__ WTH, ushort* __restrict__ WTL,
                                                 int K, int F) {
  __shared__ float tile[32][33];
  const int k0 = blockIdx.x * 32;
  const int n0 = blockIdx.y * 32;
  const int t = threadIdx.x;
  {
    const int r = t >> 3, cq = t & 7;
    const int srcRow = (n0 < F) ? (k0 + r) : (K + k0 + r);
    const int srcCol = (n0 < F) ? n0 : (n0 - F);
    float4 v = *(const float4*)(W + (size_t)srcRow * F + srcCol + cq * 4);
    tile[r][cq * 4 + 0] = v.x; tile[r][cq * 4 + 1] = v.y;
    tile[r][cq * 4 + 2] = v.z; tile[r][cq * 4 + 3] = v.w;
  }
  __syncthreads();
  {
    const int nl = t >> 3, kq = t & 7;
    ushort h[4], l[4];
#pragma unroll
    for (int i = 0; i < 4; ++i) split2(tile[kq * 4 + i][nl], h[i], l[i]);
    ushort4 vh = {h[0], h[1], h[2], h[3]};
    ushort4 vl = {l[0], l[1], l[2], l[3]};
    *(ushort4*)(WTH + (size_t)(n0 + nl) * K + k0 + kq * 4) = vh;
    *(ushort4*)(WTL + (size_t)(n0 + nl) * K + k0 + kq * 4) = vl;
  }
}

// ---------------- K6: layer epilogue ----------------
__global__ __launch_bounds__(256) void k_postlayer(const float* __restrict__ C, const float* __restrict__ adj,
                                                   const float* __restrict__ bias,
                                                   ushort* __restrict__ HH, ushort* __restrict__ HL, int F) {
  __shared__ float adjL[64 * 65];
  __shared__ float QL[64 * 66];
  const int f0 = blockIdx.x * 64;
  const int b = blockIdx.y;
  const int t = threadIdx.x;
  const int fc = t & 63, rg = t >> 6;
  const int twoF = 2 * F;
  for (int i = t; i < 4096; i += 256) {
    const int r = i >> 6, j = i & 63;
    adjL[r * 65 + j] = adj[(size_t)b * 4096 + i];
    QL[r * 66 + j] = C[(size_t)(b * 64 + r) * twoF + F + f0 + j];
  }
  __syncthreads();
  const float bv = bias[f0 + fc];
  for (int rr = 0; rr < 16; ++rr) {
    const int r = rg * 16 + rr;
    float s = 0.f;
#pragma unroll 8
    for (int j0 = 0; j0 < 64; ++j0) {
      const int j = (j0 + fc) & 63;
      s += adjL[r * 65 + j] * QL[j * 66 + fc];
    }
    const int row = b * 64 + r;
    float h = C[(size_t)row * twoF + f0 + fc] + s + bv;
    h = fmaxf(h, 0.f);
    ushort hh, hl;
    split2(h, hh, hl);
    HH[(size_t)row * F + f0 + fc] = hh;
    HL[(size_t)row * F + f0 + fc] = hl;
  }
}

// ---------------- K8: pred = prelu(CBUF + bc1) @ Wc2 + bc2 (fused classifier tail) ----------------
__global__ __launch_bounds__(256) void k_final2(const float* __restrict__ C, const float* __restrict__ bc1,
                                                const float* __restrict__ pre, const float* __restrict__ Wc2,
                                                const float* __restrict__ bc2, float* __restrict__ outp) {
  __shared__ float w[512];
  __shared__ float red[512];
  const int t = threadIdx.x;
  for (int i = t; i < 512; i += 256) w[i] = Wc2[i];
  __syncthreads();
  const int m = blockIdx.x * 64 + (t >> 2);
  const int p = t & 3;
  const float* h = C + (size_t)m * 256;
  float s0 = 0.f, s1 = 0.f;
  for (int k = p * 64; k < p * 64 + 64; ++k) {
    float hv = h[k] + bc1[k];
    hv = (hv > 0.f) ? hv : pre[k] * hv;
    s0 += hv * w[k * 2];
    s1 += hv * w[k * 2 + 1];
  }
  red[t * 2] = s0; red[t * 2 + 1] = s1;
  __syncthreads();
  if (p == 0) {
    for (int q = 1; q < 4; ++q) { s0 += red[(t + q) * 2]; s1 += red[(t + q) * 2 + 1]; }
    outp[m * 2 + 0] = s0 + bc2[0];
    outp[m * 2 + 1] = s1 + bc2[1];
  }
}

extern "C" void kernel_launch(void* const* d_in, const int* in_sizes, int n_in,
                              void* d_out, int out_size, void* d_ws, size_t ws_size,
                              hipStream_t stream) {
  const int*   indexes = (const int*)d_in[0];
  const float* F   = (const float*)d_in[1];
  const float* W1  = (const float*)d_in[4];
  const float* b1  = (const float*)d_in[5];
  const float* W2  = (const float*)d_in[6];
  const float* b2  = (const float*)d_in[7];
  const float* W3  = (const float*)d_in[8];
  const float* b3  = (const float*)d_in[9];
  const float* W4  = (const float*)d_in[10];
  const float* b4  = (const float*)d_in[11];
  const float* Wc1 = (const float*)d_in[12];
  const float* bc1 = (const float*)d_in[13];
  const float* pre = (const float*)d_in[14];
  const float* Wc2 = (const float*)d_in[15];
  const float* bc2 = (const float*)d_in[16];
  float* out = (float*)d_out;

  size_t off = 0;
  auto take = [&](size_t bytes) -> char* {
    char* q = (char*)d_ws + off;
    off += (bytes + 255) & ~(size_t)255;
    return q;
  };
  float* TOPV = (float*)take((size_t)NROWS * KSEL * 4);
  int*   TOPI = (int*)  take((size_t)NROWS * KSEL * 4);
  float* EXPS = (float*)take((size_t)NROWS * 4);
  float* ADJ  = (float*)take((size_t)64 * 64 * 64 * 4);
  char*  big  = (char*)d_ws + off;
  const size_t big_bytes = (ws_size > off) ? (ws_size - off) : 0;

  const size_t Mi = 1024 * 1024;
  const size_t Ki = 1024;
  const size_t splitBytes = (size_t)NROWS * DFEAT * 2;  // 32 Mi per split
  const size_t TSZ = (size_t)CHK * CHK;                 // floats per tile (16 Mi)

  auto enc = [](int ci, int cj, int ba, int bb, int dg) {
    return ci | (cj << 4) | (ba << 8) | (bb << 12) | (dg << 16);
  };

  if (big_bytes >= 224 * Mi) {
    // ---- 8-buffer path: 4 stream-lean sim launches + 2 merged update launches ----
    ushort* FH = (ushort*)big;
    ushort* FM = (ushort*)(big + splitBytes);
    ushort* FL = (ushort*)(big + 2 * splitBytes);
    float* BUFS = (float*)(big + 96 * Mi);   // 8 buffers of 16 Mi
    k_split<<<NROWS * DFEAT / 1024, 256, 0, stream>>>(F, FH, FM, FL);
    k_init_topk<<<NROWS * KSEL / 256, 256, 0, stream>>>(TOPV, TOPI);
    // D: 4 diagonal tiles -> bufs 0-3 (in-place mirror)
    k_sim_batch<<<dim3(16, 16, 4), 256, 0, stream>>>(FH, FM, FL, BUFS,
        enc(0,0,0,0,1), enc(1,1,1,1,1), enc(2,2,2,2,1), enc(3,3,3,3,1), 0, 0);
    // G0: (0,1) -> bufs 4,5 ; (2,3) -> bufs 6,7
    k_sim_batch<<<dim3(16, 16, 2), 256, 0, stream>>>(FH, FM, FL, BUFS,
        enc(0,1,4,5,0), enc(2,3,6,7,0), 0, 0, 0, 0);
    // merged: row r <- (buf r, col r) + (buf 4+r, col [1,0,3,2][r])
    k_topk_upd2<<<dim3(CHK, 4), 256, 0, stream>>>(BUFS,
        0, 1, 2, 3,  0, 1, 2, 3,
        4, 5, 6, 7,  1, 0, 3, 2, TOPV, TOPI);
    // G1: (0,2) -> bufs 0,1 ; (1,3) -> bufs 2,3  (D results already consumed)
    k_sim_batch<<<dim3(16, 16, 2), 256, 0, stream>>>(FH, FM, FL, BUFS,
        enc(0,2,0,1,0), enc(1,3,2,3,0), 0, 0, 0, 0);
    // G2: (0,3) -> bufs 4,5 ; (1,2) -> bufs 6,7  (G0 results already consumed)
    k_sim_batch<<<dim3(16, 16, 2), 256, 0, stream>>>(FH, FM, FL, BUFS,
        enc(0,3,4,5,0), enc(1,2,6,7,0), 0, 0, 0, 0);
    // merged: row0 <- (buf0,c2)+(buf4,c3); row1 <- (buf2,c3)+(buf6,c2);
    //         row2 <- (buf1,c0)+(buf7,c1); row3 <- (buf3,c1)+(buf5,c0)
    k_topk_upd2<<<dim3(CHK, 4), 256, 0, stream>>>(BUFS,
        0, 2, 1, 3,  2, 3, 0, 1,
        4, 6, 7, 5,  3, 2, 1, 0, TOPV, TOPI);
    k_exps<<<NROWS / 256, 256, 0, stream>>>(TOPV, EXPS);
  } else if (big_bytes >= 160 * Mi) {
    // ---- 4-buffer path (R11 schedule) ----
    ushort* FH = (ushort*)big;
    ushort* FM = (ushort*)(big + splitBytes);
    ushort* FL = (ushort*)(big + 2 * splitBytes);
    float* BUFS = (float*)(big + 96 * Mi);   // 4 buffers of 16 Mi
    k_split<<<NROWS * DFEAT / 1024, 256, 0, stream>>>(F, FH, FM, FL);
    k_init_topk<<<NROWS * KSEL / 256, 256, 0, stream>>>(TOPV, TOPI);
    k_sim_batch<<<dim3(16, 16, 4), 256, 0, stream>>>(FH, FM, FL, BUFS,
        enc(0,0,0,0,1), enc(1,1,1,1,1), enc(2,2,2,2,1), enc(3,3,3,3,1), 0, 0);
    k_topk_upd4<<<dim3(CHK, 4), 256, 0, stream>>>(BUFS, 0, 1, 2, 3, 0, 1, 2, 3, TOPV, TOPI);
    k_sim_batch<<<dim3(16, 16, 2), 256, 0, stream>>>(FH, FM, FL, BUFS,
        enc(0,1,0,1,0), enc(2,3,2,3,0), 0, 0, 0, 0);
    k_topk_upd4<<<dim3(CHK, 4), 256, 0, stream>>>(BUFS, 0, 1, 2, 3, 1, 0, 3, 2, TOPV, TOPI);
    k_sim_batch<<<dim3(16, 16, 2), 256, 0, stream>>>(FH, FM, FL, BUFS,
        enc(0,2,0,1,0), enc(1,3,2,3,0), 0, 0, 0, 0);
    k_topk_upd4<<<dim3(CHK, 4), 256, 0, stream>>>(BUFS, 0, 2, 1, 3, 2, 3, 0, 1, TOPV, TOPI);
    k_sim_batch<<<dim3(16, 16, 2), 256, 0, stream>>>(FH, FM, FL, BUFS,
        enc(0,3,0,1,0), enc(1,2,2,3,0), 0, 0, 0, 0);
    k_topk_upd4<<<dim3(CHK, 4), 256, 0, stream>>>(BUFS, 0, 2, 3, 1, 3, 2, 1, 0, TOPV, TOPI);
    k_exps<<<NROWS / 256, 256, 0, stream>>>(TOPV, EXPS);
  } else {
    int fchunk = 0;
    for (int c = 2048; c >= 512; c >>= 1) {
      if (3 * splitBytes + (size_t)c * NROWS * 4 <= big_bytes) { fchunk = c; break; }
    }
    if (fchunk == 0) {
      hipMemsetAsync(d_out, 0, (size_t)out_size * 4, stream);
      return;
    }
    ushort* FH = (ushort*)big;
    ushort* FM = (ushort*)(big + splitBytes);
    ushort* FL = (ushort*)(big + 2 * splitBytes);
    float* SIMC = (float*)(big + 3 * splitBytes);
    k_split<<<NROWS * DFEAT / 1024, 256, 0, stream>>>(F, FH, FM, FL);
    for (int r0 = 0; r0 < NROWS; r0 += fchunk) {
      k_simgemm_mfma<<<dim3(64, fchunk / 128), 256, 0, stream>>>(FH, FM, FL, SIMC, r0);
      k_topk<<<fchunk, 256, 0, stream>>>(SIMC, TOPV, TOPI, EXPS, r0);
    }
  }
  k_adj<<<64, 256, 0, stream>>>(indexes, TOPV, TOPI, EXPS, ADJ);

  // ---- phase B (aliases phase-A region; lifetime-checked) ----
  ushort* XH   = (ushort*)(big);
  ushort* XL   = (ushort*)(big + 16 * Mi);
  ushort* WT1H = (ushort*)(big + 32 * Mi);
  ushort* WT1L = (ushort*)(big + 40 * Mi);
  ushort* WT2H = (ushort*)(big + 48 * Mi);
  ushort* WT2L = (ushort*)(big + 50 * Mi);
  ushort* WT3H = (ushort*)(big + 52 * Mi);
  ushort* WT3L = (ushort*)(big + 52 * Mi + 512 * Ki);
  ushort* WT4H = (ushort*)(big + 53 * Mi);
  ushort* WT4L = (ushort*)(big + 53 * Mi + 256 * Ki);
  ushort* WTcH = (ushort*)(big + 53 * Mi + 512 * Ki);
  ushort* WTcL = (ushort*)(big + 53 * Mi + 640 * Ki);
  float*  CBUF = (float*)(big + 54 * Mi);
  ushort* H1H  = (ushort*)(big + 32 * Mi);
  ushort* H1L  = (ushort*)(big + 40 * Mi);
  ushort* H2H  = (ushort*)(big);
  ushort* H2L  = (ushort*)(big + 4 * Mi);
  ushort* H3H  = (ushort*)(big + 8 * Mi);
  ushort* H3L  = (ushort*)(big + 10 * Mi);
  ushort* H4H  = (ushort*)(big + 12 * Mi);
  ushort* H4L  = (ushort*)(big + 14 * Mi);

  k_wsplitT<<<dim3(2048 / 32, 2048 / 32), 256, 0, stream>>>(W1, WT1H, WT1L, 2048, 1024);
  k_wsplitT<<<dim3(1024 / 32, 1024 / 32), 256, 0, stream>>>(W2, WT2H, WT2L, 1024, 512);
  k_wsplitT<<<dim3(512 / 32, 512 / 32), 256, 0, stream>>>(W3, WT3H, WT3L, 512, 256);
  k_wsplitT<<<dim3(256 / 32, 512 / 32), 256, 0, stream>>>(W4, WT4H, WT4L, 256, 256);
  k_wsplitT<<<dim3(256 / 32, 256 / 32), 256, 0, stream>>>(Wc1, WTcH, WTcL, 256, 256);

  k_xs_split<<<dim3(64, 64), 256, 0, stream>>>(indexes, TOPI, F, XH, XL);

  k_gemm3<<<dim3(16, 32), 256, 0, stream>>>(XH, XL, WT1H, WT1L, CBUF, 2048, 2048);
  k_postlayer<<<dim3(16, 64), 256, 0, stream>>>(CBUF, ADJ, b1, H1H, H1L, 1024);
  k_gemm3<<<dim3(8, 32), 256, 0, stream>>>(H1H, H1L, WT2H, WT2L, CBUF, 1024, 1024);
  k_postlayer<<<dim3(8, 64), 256, 0, stream>>>(CBUF, ADJ, b2, H2H, H2L, 512);
  k_gemm3<<<dim3(4, 32), 256, 0, stream>>>(H2H, H2L, WT3H, WT3L, CBUF, 512, 512);
  k_postlayer<<<dim3(4, 64), 256, 0, stream>>>(CBUF, ADJ, b3, H3H, H3L, 256);
  k_gemm3<<<dim3(4, 32), 256, 0, stream>>>(H3H, H3L, WT4H, WT4L, CBUF, 256, 512);
  k_postlayer<<<dim3(4, 64), 256, 0, stream>>>(CBUF, ADJ, b4, H4H, H4L, 256);
  k_gemm3<<<dim3(2, 32), 256, 0, stream>>>(H4H, H4L, WTcH, WTcL, CBUF, 256, 256);
  k_final2<<<64, 256, 0, stream>>>(CBUF, bc1, pre, Wc2, bc2, out);
}

// Round 18
// 1457.481 us; speedup vs baseline: 1.0102x; 1.0102x over previous
//
#include <hip/hip_runtime.h>
#include <hip/hip_bf16.h>
#include <math.h>

#define NROWS 8192
#define DFEAT 2048
#define KSEL  64
#define CHK   2048   // symmetric pair chunk

typedef unsigned long long u64;
typedef __attribute__((ext_vector_type(8))) short bf16x8;
typedef __attribute__((ext_vector_type(4))) float f32x4;

__device__ __forceinline__ u64 umax64(u64 a, u64 b) { return a > b ? a : b; }

__device__ __forceinline__ void split2(float v, ushort& h, ushort& l) {
  __hip_bfloat16 bh = __float2bfloat16(v);
  float r = v - __bfloat162float(bh);
  __hip_bfloat16 bl = __float2bfloat16(r);
  h = *(ushort*)&bh; l = *(ushort*)&bl;
}

__device__ __forceinline__ u64 mkkey_vi(float v, int i) {
  unsigned u = __float_as_uint(v);
  u = ((int)u < 0) ? ~u : (u | 0x80000000u);
  return ((u64)u << 32) | (u64)(0xFFFFFFFFu - (unsigned)i);
}

// ---------------- K0: 3-way bf16 split of F (exact to 2^-27) ----------------
__global__ __launch_bounds__(256) void k_split(const float* __restrict__ F, ushort* __restrict__ H,
                                               ushort* __restrict__ M, ushort* __restrict__ L) {
  const size_t i0 = ((size_t)blockIdx.x * 256 + threadIdx.x) * 4;
  float4 x = *(const float4*)(F + i0);
  float xs[4] = {x.x, x.y, x.z, x.w};
  ushort h[4], m[4], l[4];
#pragma unroll
  for (int c = 0; c < 4; ++c) {
    float v = xs[c];
    __hip_bfloat16 bh = __float2bfloat16(v);
    float r1 = v - __bfloat162float(bh);
    __hip_bfloat16 bm = __float2bfloat16(r1);
    float r2 = r1 - __bfloat162float(bm);
    __hip_bfloat16 bl = __float2bfloat16(r2);
    h[c] = *(ushort*)&bh; m[c] = *(ushort*)&bm; l[c] = *(ushort*)&bl;
  }
  ushort4 vh = {h[0], h[1], h[2], h[3]};
  ushort4 vm = {m[0], m[1], m[2], m[3]};
  ushort4 vl = {l[0], l[1], l[2], l[3]};
  *(ushort4*)(H + i0) = vh;
  *(ushort4*)(M + i0) = vm;
  *(ushort4*)(L + i0) = vl;
}

// ---------------- K1x: batched sim tiles (bf16x6, swizzled LDS) — proven R13 kernel ----------------
// Per-z table entry e: ci | cj<<4 | bufA<<8 | bufB<<12 | diag<<16.
__global__ __launch_bounds__(256) void k_sim_batch(
    const ushort* __restrict__ FH, const ushort* __restrict__ FM, const ushort* __restrict__ FL,
    float* __restrict__ BUFS, int e0, int e1, int e2, int e3, int e4, int e5) {
  __shared__ ushort lds[6 * 4096];
  const int z = blockIdx.z;
  const int e = (z == 0) ? e0 : ((z == 1) ? e1 : ((z == 2) ? e2 : ((z == 3) ? e3 : ((z == 4) ? e4 : e5))));
  const int ci = e & 15, cj = (e >> 4) & 15;
  const int bA = (e >> 8) & 15, bB = (e >> 12) & 15;
  const int diag = (e >> 16) & 1;
  const int bj = blockIdx.x;
  const int bm = blockIdx.y;
  if (diag && bm > bj) return;
  const size_t TSZ = (size_t)CHK * CHK;
  float* TILE = BUFS + (size_t)bA * TSZ;
  float* TILT = BUFS + (size_t)bB * TSZ;
  const int t = threadIdx.x;
  const int w = t >> 6, l = t & 63;
  const int arow0 = ci * CHK + bm * 128;
  const int brow0 = cj * CHK + bj * 128;
  const int segr = l >> 2;
  const int segq_s = (l & 3) ^ ((l >> 3) & 3);
  const int fl15 = l & 15, fq = l >> 4;
  const int kswz = (fq ^ ((fl15 >> 1) & 3)) * 8;
  const int wr = w >> 1, wc = w & 1;
  const int mb = wr * 64, nb = wc * 64;

  f32x4 acc[4][4];
#pragma unroll
  for (int i = 0; i < 4; ++i)
#pragma unroll
    for (int j = 0; j < 4; ++j) acc[i][j] = (f32x4){0.f, 0.f, 0.f, 0.f};

  for (int k0 = 0; k0 < DFEAT; k0 += 32) {
    __syncthreads();
#pragma unroll
    for (int c = 0; c < 12; ++c) {
      const int cidx = w * 12 + c;
      const int tt = cidx >> 3;
      const int p = cidx & 7;
      const int rowbase = (tt < 3) ? arow0 : brow0;
      const int sp = (tt < 3) ? tt : (tt - 3);
      const ushort* sel = (sp == 0) ? FH : ((sp == 1) ? FM : FL);
      const ushort* g = sel + (size_t)(rowbase + p * 16 + segr) * DFEAT + (k0 + segq_s * 8);
      __builtin_amdgcn_global_load_lds((const __attribute__((address_space(1))) unsigned int*)g,
                                       (__attribute__((address_space(3))) unsigned int*)&lds[tt * 4096 + p * 512],
                                       16, 0, 0);
    }
    __syncthreads();

    bf16x8 af[3][4];
    bf16x8 bg[3][4];
#pragma unroll
    for (int i = 0; i < 3; ++i)
#pragma unroll
      for (int fm = 0; fm < 4; ++fm)
        af[i][fm] = *(const bf16x8*)&lds[i * 4096 + (mb + fm * 16 + fl15) * 32 + kswz];
#pragma unroll
    for (int j = 0; j < 3; ++j)
#pragma unroll
      for (int fn = 0; fn < 4; ++fn)
        bg[j][fn] = *(const bf16x8*)&lds[(3 + j) * 4096 + (nb + fn * 16 + fl15) * 32 + kswz];

#pragma unroll
    for (int fm = 0; fm < 4; ++fm)
#pragma unroll
      for (int fn = 0; fn < 4; ++fn) {
        f32x4 a = acc[fm][fn];
        a = __builtin_amdgcn_mfma_f32_16x16x32_bf16(af[0][fm], bg[0][fn], a, 0, 0, 0);
        a = __builtin_amdgcn_mfma_f32_16x16x32_bf16(af[1][fm], bg[0][fn], a, 0, 0, 0);
        a = __builtin_amdgcn_mfma_f32_16x16x32_bf16(af[0][fm], bg[1][fn], a, 0, 0, 0);
        a = __builtin_amdgcn_mfma_f32_16x16x32_bf16(af[2][fm], bg[0][fn], a, 0, 0, 0);
        a = __builtin_amdgcn_mfma_f32_16x16x32_bf16(af[0][fm], bg[2][fn], a, 0, 0, 0);
        a = __builtin_amdgcn_mfma_f32_16x16x32_bf16(af[1][fm], bg[1][fn], a, 0, 0, 0);
        acc[fm][fn] = a;
      }
  }

  const bool doT = !(diag && bm == bj);
#pragma unroll
  for (int fm = 0; fm < 4; ++fm) {
    const int lm = bm * 128 + mb + fm * 16 + fq * 4;
#pragma unroll
    for (int fn = 0; fn < 4; ++fn) {
      const int col = bj * 128 + nb + fn * 16 + fl15;
#pragma unroll
      for (int r = 0; r < 4; ++r)
        TILE[(size_t)(lm + r) * CHK + col] = acc[fm][fn][r];
      if (doT) {
        float4 v = make_float4(acc[fm][fn][0], acc[fm][fn][1], acc[fm][fn][2], acc[fm][fn][3]);
        *(float4*)(TILT + (size_t)col * CHK + lm) = v;
      }
    }
  }
}

// ---------------- K1: chunked row-panel sim (small-ws fallback) ----------------
__global__ __launch_bounds__(256) void k_simgemm_mfma(
    const ushort* __restrict__ FH, const ushort* __restrict__ FM, const ushort* __restrict__ FL,
    float* __restrict__ C, int row0) {
  __shared__ ushort lds[6 * 4096];
  const int bj = blockIdx.x;
  const int bm = blockIdx.y;
  const int t = threadIdx.x;
  const int w = t >> 6, l = t & 63;
  const int arow0 = row0 + bm * 128;
  const int brow0 = bj * 128;
  const int segr = l >> 2;
  const int segq = l & 3;
  const int fl15 = l & 15, fq = l >> 4;
  const int wr = w >> 1, wc = w & 1;
  const int mb = wr * 64, nb = wc * 64;

  f32x4 acc[4][4];
#pragma unroll
  for (int i = 0; i < 4; ++i)
#pragma unroll
    for (int j = 0; j < 4; ++j) acc[i][j] = (f32x4){0.f, 0.f, 0.f, 0.f};

  for (int k0 = 0; k0 < DFEAT; k0 += 32) {
    __syncthreads();
#pragma unroll
    for (int c = 0; c < 12; ++c) {
      const int cc = w * 12 + c;
      const int tt = cc >> 3;
      const int p = cc & 7;
      const int rowbase = (tt < 3) ? arow0 : brow0;
      const int sp = (tt < 3) ? tt : (tt - 3);
      const ushort* sel = (sp == 0) ? FH : ((sp == 1) ? FM : FL);
      const ushort* g = sel + (size_t)(rowbase + p * 16 + segr) * DFEAT + (k0 + segq * 8);
      __builtin_amdgcn_global_load_lds((const __attribute__((address_space(1))) unsigned int*)g,
                                       (__attribute__((address_space(3))) unsigned int*)&lds[tt * 4096 + p * 512],
                                       16, 0, 0);
    }
    __syncthreads();

    bf16x8 af[3][4];
    bf16x8 bg[3][4];
    const int kcol = fq * 8;
#pragma unroll
    for (int i = 0; i < 3; ++i)
#pragma unroll
      for (int fm = 0; fm < 4; ++fm)
        af[i][fm] = *(const bf16x8*)&lds[i * 4096 + (mb + fm * 16 + fl15) * 32 + kcol];
#pragma unroll
    for (int j = 0; j < 3; ++j)
#pragma unroll
      for (int fn = 0; fn < 4; ++fn)
        bg[j][fn] = *(const bf16x8*)&lds[(3 + j) * 4096 + (nb + fn * 16 + fl15) * 32 + kcol];

#pragma unroll
    for (int fm = 0; fm < 4; ++fm)
#pragma unroll
      for (int fn = 0; fn < 4; ++fn) {
        f32x4 a = acc[fm][fn];
        a = __builtin_amdgcn_mfma_f32_16x16x32_bf16(af[0][fm], bg[0][fn], a, 0, 0, 0);
        a = __builtin_amdgcn_mfma_f32_16x16x32_bf16(af[1][fm], bg[0][fn], a, 0, 0, 0);
        a = __builtin_amdgcn_mfma_f32_16x16x32_bf16(af[0][fm], bg[1][fn], a, 0, 0, 0);
        a = __builtin_amdgcn_mfma_f32_16x16x32_bf16(af[2][fm], bg[0][fn], a, 0, 0, 0);
        a = __builtin_amdgcn_mfma_f32_16x16x32_bf16(af[0][fm], bg[2][fn], a, 0, 0, 0);
        a = __builtin_amdgcn_mfma_f32_16x16x32_bf16(af[1][fm], bg[1][fn], a, 0, 0, 0);
        acc[fm][fn] = a;
      }
  }

#pragma unroll
  for (int fm = 0; fm < 4; ++fm) {
    const int lm = bm * 128 + mb + fm * 16 + fq * 4;
#pragma unroll
    for (int fn = 0; fn < 4; ++fn) {
      const int col = bj * 128 + nb + fn * 16 + fl15;
#pragma unroll
      for (int r = 0; r < 4; ++r)
        C[(size_t)(lm + r) * NROWS + col] = acc[fm][fn][r];
    }
  }
}

// ---------------- K1b: generic bf16x3 MFMA GEMM: C = A . B^T (swizzled LDS) ----------------
__global__ __launch_bounds__(256) void k_gemm3(const ushort* __restrict__ AH, const ushort* __restrict__ AL,
                                               const ushort* __restrict__ BH, const ushort* __restrict__ BL,
                                               float* __restrict__ C, int K, int N) {
  __shared__ ushort lds[4 * 4096];
  const int bj = blockIdx.x, bm = blockIdx.y;
  const int t = threadIdx.x;
  const int w = t >> 6, l = t & 63;
  const int segr = l >> 2;
  const int segq_s = (l & 3) ^ ((l >> 3) & 3);
  const int fl15 = l & 15, fq = l >> 4;
  const int kswz = (fq ^ ((fl15 >> 1) & 3)) * 8;
  const int wr = w >> 1, wc = w & 1;
  const int mb = wr * 64, nb = wc * 64;

  f32x4 acc[4][4];
#pragma unroll
  for (int i = 0; i < 4; ++i)
#pragma unroll
    for (int j = 0; j < 4; ++j) acc[i][j] = (f32x4){0.f, 0.f, 0.f, 0.f};

  for (int k0 = 0; k0 < K; k0 += 32) {
    __syncthreads();
#pragma unroll
    for (int c = 0; c < 8; ++c) {
      const int s = w * 8 + c;
      const int tt = s >> 3;
      const int p = s & 7;
      const int rowbase = (tt < 2) ? (bm * 128) : (bj * 128);
      const ushort* sel = (tt == 0) ? AH : ((tt == 1) ? AL : ((tt == 2) ? BH : BL));
      const ushort* g = sel + (size_t)(rowbase + p * 16 + segr) * K + (k0 + segq_s * 8);
      __builtin_amdgcn_global_load_lds((const __attribute__((address_space(1))) unsigned int*)g,
                                       (__attribute__((address_space(3))) unsigned int*)&lds[s * 512],
                                       16, 0, 0);
    }
    __syncthreads();

    bf16x8 af[2][4];
    bf16x8 bg[2][4];
#pragma unroll
    for (int i = 0; i < 2; ++i)
#pragma unroll
      for (int fm = 0; fm < 4; ++fm)
        af[i][fm] = *(const bf16x8*)&lds[i * 4096 + (mb + fm * 16 + fl15) * 32 + kswz];
#pragma unroll
    for (int j = 0; j < 2; ++j)
#pragma unroll
      for (int fn = 0; fn < 4; ++fn)
        bg[j][fn] = *(const bf16x8*)&lds[(2 + j) * 4096 + (nb + fn * 16 + fl15) * 32 + kswz];

#pragma unroll
    for (int fm = 0; fm < 4; ++fm)
#pragma unroll
      for (int fn = 0; fn < 4; ++fn) {
        f32x4 a = acc[fm][fn];
        a = __builtin_amdgcn_mfma_f32_16x16x32_bf16(af[0][fm], bg[0][fn], a, 0, 0, 0);
        a = __builtin_amdgcn_mfma_f32_16x16x32_bf16(af[0][fm], bg[1][fn], a, 0, 0, 0);
        a = __builtin_amdgcn_mfma_f32_16x16x32_bf16(af[1][fm], bg[0][fn], a, 0, 0, 0);
        acc[fm][fn] = a;
      }
  }

#pragma unroll
  for (int fm = 0; fm < 4; ++fm) {
    const int row = bm * 128 + mb + fm * 16 + fq * 4;
#pragma unroll
    for (int fn = 0; fn < 4; ++fn) {
      const int col = bj * 128 + nb + fn * 16 + fl15;
#pragma unroll
      for (int r = 0; r < 4; ++r)
        C[(size_t)(row + r) * N + col] = acc[fm][fn][r];
    }
  }
}

// ---------------- K2i: init running top-k ----------------
__global__ __launch_bounds__(256) void k_init_topk(float* __restrict__ topv, int* __restrict__ topi) {
  const int i = blockIdx.x * 256 + threadIdx.x;
  topv[i] = -INFINITY;
  topi[i] = 0;
}

// ---------------- K2u2: merged update — TWO 2048-col sources + old 64 -> new top-64 ----------------
__global__ __launch_bounds__(256) void k_topk_upd2(const float* __restrict__ bufbase,
                                                   int a0, int a1, int a2, int a3,
                                                   int ca0, int ca1, int ca2, int ca3,
                                                   int b0, int b1, int b2, int b3,
                                                   int cb0, int cb1, int cb2, int cb3,
                                                   float* __restrict__ topv, int* __restrict__ topi) {
  __shared__ unsigned cnt[64];
  __shared__ unsigned nsel;
  __shared__ u64 selbuf[64];
  const int t = threadIdx.x;
  const int y = blockIdx.y;
  const int bA = (y == 0) ? a0 : ((y == 1) ? a1 : ((y == 2) ? a2 : a3));
  const int cA = (y == 0) ? ca0 : ((y == 1) ? ca1 : ((y == 2) ? ca2 : ca3));
  const int bB = (y == 0) ? b0 : ((y == 1) ? b1 : ((y == 2) ? b2 : b3));
  const int cB = (y == 0) ? cb0 : ((y == 1) ? cb1 : ((y == 2) ? cb2 : cb3));
  const size_t TSZ = (size_t)CHK * CHK;
  const int row = y * CHK + blockIdx.x;
  const float* srcA = bufbase + (size_t)bA * TSZ + (size_t)blockIdx.x * CHK;
  const float* srcB = bufbase + (size_t)bB * TSZ + (size_t)blockIdx.x * CHK;

  if (t < 64) cnt[t] = 0;
  if (t == 0) nsel = 0;

  u64 k[17];
  int nk = 16;
#pragma unroll
  for (int q = 0; q < 8; ++q) {
    k[q] = mkkey_vi(srcA[t + 256 * q], cA * CHK + t + 256 * q);
    k[8 + q] = mkkey_vi(srcB[t + 256 * q], cB * CHK + t + 256 * q);
  }
  k[16] = 0;
  if (t < 64) {
    k[16] = mkkey_vi(topv[(size_t)row * KSEL + t], topi[(size_t)row * KSEL + t]);
    nk = 17;
  }
  __syncthreads();

  u64 T64 = 0;
  for (int bit = 63; bit >= 0; --bit) {
    const u64 cand = T64 | (1ull << bit);
    unsigned c = 0;
#pragma unroll
    for (int q = 0; q < 17; ++q) c += (q < nk && k[q] >= cand) ? 1u : 0u;
#pragma unroll
    for (int s = 32; s > 0; s >>= 1) c += __shfl_down(c, s);
    if ((t & 63) == 0) atomicAdd(&cnt[bit], c);
    __syncthreads();
    const unsigned cb = cnt[bit];
    if (cb >= 64) T64 = cand;
    if (cb == 64) break;
  }

#pragma unroll
  for (int q = 0; q < 17; ++q) {
    if (q < nk && k[q] >= T64) {
      unsigned p = atomicAdd(&nsel, 1u);
      if (p < 64) selbuf[p] = k[q];
    }
  }
  __syncthreads();

  if (t < 64) {
    u64 key = selbuf[t];
#pragma unroll
    for (int kk = 2; kk <= 64; kk <<= 1) {
#pragma unroll
      for (int j = kk >> 1; j > 0; j >>= 1) {
        u64 other = __shfl_xor(key, j);
        const bool dirDesc = ((t & kk) == 0);
        const bool upper = ((t & j) != 0);
        u64 mx = umax64(key, other);
        u64 mn = (key < other) ? key : other;
        key = (dirDesc ^ upper) ? mx : mn;
      }
    }
    const unsigned ui = (unsigned)(key >> 32);
    const float v = __uint_as_float((ui & 0x80000000u) ? (ui ^ 0x80000000u) : ~ui);
    const int idx = (int)(0xFFFFFFFFu - (unsigned)(key & 0xFFFFFFFFull));
    topv[(size_t)row * KSEL + t] = v;
    topi[(size_t)row * KSEL + t] = idx;
  }
}

// shared body: merge one 2048-col source + old 64 -> new top-64 (4-buffer path)
__device__ __forceinline__ void topk_merge_body(const float* src, int row, int colbase,
                                                float* topv, int* topi,
                                                unsigned* cnt, unsigned* nselp, u64* selbuf) {
  const int t = threadIdx.x;
  if (t < 64) cnt[t] = 0;
  if (t == 0) *nselp = 0;

  u64 k[9];
  int nk = 8;
#pragma unroll
  for (int q = 0; q < 8; ++q) {
    float v = src[t + 256 * q];
    k[q] = mkkey_vi(v, colbase + t + 256 * q);
  }
  k[8] = 0;
  if (t < 64) {
    k[8] = mkkey_vi(topv[(size_t)row * KSEL + t], topi[(size_t)row * KSEL + t]);
    nk = 9;
  }
  __syncthreads();

  u64 T64 = 0;
  for (int bit = 63; bit >= 0; --bit) {
    const u64 cand = T64 | (1ull << bit);
    unsigned c = 0;
#pragma unroll
    for (int q = 0; q < 9; ++q) c += (q < nk && k[q] >= cand) ? 1u : 0u;
#pragma unroll
    for (int s = 32; s > 0; s >>= 1) c += __shfl_down(c, s);
    if ((t & 63) == 0) atomicAdd(&cnt[bit], c);
    __syncthreads();
    const unsigned cb = cnt[bit];
    if (cb >= 64) T64 = cand;
    if (cb == 64) break;
  }

#pragma unroll
  for (int q = 0; q < 9; ++q) {
    if (q < nk && k[q] >= T64) {
      unsigned p = atomicAdd(nselp, 1u);
      if (p < 64) selbuf[p] = k[q];
    }
  }
  __syncthreads();

  if (t < 64) {
    u64 key = selbuf[t];
#pragma unroll
    for (int kk = 2; kk <= 64; kk <<= 1) {
#pragma unroll
      for (int j = kk >> 1; j > 0; j >>= 1) {
        u64 other = __shfl_xor(key, j);
        const bool dirDesc = ((t & kk) == 0);
        const bool upper = ((t & j) != 0);
        u64 mx = umax64(key, other);
        u64 mn = (key < other) ? key : other;
        key = (dirDesc ^ upper) ? mx : mn;
      }
    }
    const unsigned ui = (unsigned)(key >> 32);
    const float v = __uint_as_float((ui & 0x80000000u) ? (ui ^ 0x80000000u) : ~ui);
    const int idx = (int)(0xFFFFFFFFu - (unsigned)(key & 0xFFFFFFFFull));
    topv[(size_t)row * KSEL + t] = v;
    topi[(size_t)row * KSEL + t] = idx;
  }
}

// ---------------- K2u4: single-source update (4-buffer path) ----------------
__global__ __launch_bounds__(256) void k_topk_upd4(const float* __restrict__ bufbase,
                                                   int b0, int b1, int b2, int b3,
                                                   int c0, int c1, int c2, int c3,
                                                   float* __restrict__ topv, int* __restrict__ topi) {
  __shared__ unsigned cnt[64];
  __shared__ unsigned nsel;
  __shared__ u64 selbuf[64];
  const int y = blockIdx.y;
  const int bi = (y == 0) ? b0 : ((y == 1) ? b1 : ((y == 2) ? b2 : b3));
  const int cc = (y == 0) ? c0 : ((y == 1) ? c1 : ((y == 2) ? c2 : c3));
  const size_t TSZ = (size_t)CHK * CHK;
  const float* src = bufbase + (size_t)bi * TSZ + (size_t)blockIdx.x * CHK;
  topk_merge_body(src, y * CHK + blockIdx.x, cc * CHK, topv, topi, cnt, &nsel, selbuf);
}

// ---------------- K2e: exps from final top-10 ----------------
__global__ __launch_bounds__(256) void k_exps(const float* __restrict__ topv, float* __restrict__ exps) {
  const int r = blockIdx.x * 256 + threadIdx.x;
  float s = 0.f;
#pragma unroll
  for (int q = 0; q < 10; ++q) s += topv[(size_t)r * KSEL + q];
  exps[r] = expf(s / 40.0f);
}

// ---------------- K2: full-row top-64 (small-ws fallback) ----------------
__global__ __launch_bounds__(256) void k_topk(const float* __restrict__ simc,
                                              float* __restrict__ topv, int* __restrict__ topi,
                                              float* __restrict__ exps, int row0) {
  __shared__ float vals[NROWS];
  __shared__ u64 wmax[4];
  __shared__ float outv[KSEL];
  __shared__ int outi[KSEL];
  const int row = row0 + blockIdx.x;
  const int t = threadIdx.x;
  const float* src = simc + (size_t)blockIdx.x * NROWS;
  for (int i = t; i < NROWS; i += 256) vals[i] = src[i];
  __syncthreads();

  u64 lk = 0;
#pragma unroll
  for (int m = 0; m < 32; ++m) {
    int i = t + 256 * m;
    lk = umax64(lk, mkkey_vi(vals[i], i));
  }

  const int lane = t & 63, wv = t >> 6;
  for (int it = 0; it < KSEL; ++it) {
    u64 wk = lk;
#pragma unroll
    for (int s = 32; s > 0; s >>= 1) {
      u64 o = __shfl_xor(wk, s);
      wk = umax64(wk, o);
    }
    if (lane == 0) wmax[wv] = wk;
    __syncthreads();
    u64 g = umax64(umax64(wmax[0], wmax[1]), umax64(wmax[2], wmax[3]));
    const unsigned ui = (unsigned)(g >> 32);
    const float v = __uint_as_float((ui & 0x80000000u) ? (ui ^ 0x80000000u) : ~ui);
    const int idx = (int)(0xFFFFFFFFu - (unsigned)(g & 0xFFFFFFFFull));
    if (t == 0) { outv[it] = v; outi[it] = idx; }
    if (t == (idx & 255)) {
      vals[idx] = -INFINITY;
      u64 nl = 0;
#pragma unroll
      for (int m = 0; m < 32; ++m) {
        int i = t + 256 * m;
        nl = umax64(nl, mkkey_vi(vals[i], i));
      }
      lk = nl;
    }
    __syncthreads();
  }
  if (t < KSEL) {
    topv[(size_t)row * KSEL + t] = outv[t];
    topi[(size_t)row * KSEL + t] = outi[t];
  }
  if (t == 0) {
    float s = 0.f;
#pragma unroll
    for (int q = 0; q < 10; ++q) s += outv[q];
    exps[row] = expf(s / 40.0f);
  }
}

// ---------------- K3: adjacency build + row softmax ----------------
__global__ __launch_bounds__(256) void k_adj(const int* __restrict__ indexes,
                                             const float* __restrict__ topv, const int* __restrict__ topi,
                                             const float* __restrict__ exps, float* __restrict__ adj) {
  __shared__ int nbr[64];
  __shared__ int neigh[64][10];
  __shared__ float tv[64][10];
  __shared__ float adjL[64][64];
  const int b = blockIdx.x;
  const int t = threadIdx.x;
  const int idx = indexes[b];
  if (t < 64) nbr[t] = topi[(size_t)idx * KSEL + t];
  __syncthreads();
  for (int p = t; p < 640; p += 256) {
    const int r = p / 10, q = p - r * 10;
    const int m = nbr[r];
    const int c = topi[(size_t)m * KSEL + q];
    neigh[r][q] = c;
    tv[r][q] = topv[(size_t)m * KSEL + q] * exps[c];
  }
  __syncthreads();
  for (int p = t; p < 4096; p += 256) {
    const int i = p >> 6, j = p & 63;
    float s = 0.f;
#pragma unroll
    for (int q = 0; q < 10; ++q) {
      const int c = neigh[i][q];
      float add = 0.f;
      for (int s2 = 0; s2 < 10; ++s2) {
        if (neigh[j][s2] == c) { add = (tv[j][s2] > 0.f) ? tv[i][q] : 0.f; break; }
      }
      s += add;
    }
    adjL[i][j] = s;
  }
  __syncthreads();
  const int wv = t >> 6, lane = t & 63;
  for (int i = wv * 16; i < wv * 16 + 16; ++i) {
    float v = adjL[i][lane];
    float mx = v;
#pragma unroll
    for (int s = 32; s > 0; s >>= 1) mx = fmaxf(mx, __shfl_xor(mx, s));
    float e = expf(v - mx);
    float sum = e;
#pragma unroll
    for (int s = 32; s > 0; s >>= 1) sum += __shfl_xor(sum, s);
    adj[((size_t)b * 64 + i) * 64 + lane] = e / sum;
  }
}

// ---------------- K4: xs splits ----------------
__global__ __launch_bounds__(256) void k_xs_split(const int* __restrict__ indexes, const int* __restrict__ topi,
                                                  const float* __restrict__ F,
                                                  ushort* __restrict__ XH, ushort* __restrict__ XL) {
  const int b = blockIdx.y, r = blockIdx.x;
  const int t = threadIdx.x;
  const int idx = indexes[b];
  const int m  = topi[(size_t)idx * KSEL + r];
  const int m0 = topi[(size_t)idx * KSEL + 0];
  const float4* pa = (const float4*)(F + (size_t)m * DFEAT);
  const float4* pb = (const float4*)(F + (size_t)m0 * DFEAT);
  const size_t rowoff = ((size_t)b * 64 + r) * DFEAT;
#pragma unroll
  for (int it = 0; it < 2; ++it) {
    const int i = t + it * 256;
    float4 a = pa[i], c = pb[i];
    float d[4] = {a.x - c.x, a.y - c.y, a.z - c.z, a.w - c.w};
    ushort h[4], l[4];
#pragma unroll
    for (int q = 0; q < 4; ++q) split2(d[q], h[q], l[q]);
    ushort4 vh = {h[0], h[1], h[2], h[3]};
    ushort4 vl = {l[0], l[1], l[2], l[3]};
    *(ushort4*)(XH + rowoff + i * 4) = vh;
    *(ushort4*)(XL + rowoff + i * 4) = vl;
  }
}

// ---------------- K5: weight pre-split, transposed + combined ----------------
__global__ __launch_bounds__(256) void k_wsplitT(const float* __restrict__ W,
                                                 ushort* __restrict__ WTH, ushort* __restrict__ WTL,
                                                 int K, int F) {
  __shared__ float tile[32][33];
  const int k0 = blockIdx.x * 32;
  const int n0 = blockIdx.y * 32;
  const int t = threadIdx.x;
  {
    const int r = t >> 3, cq = t & 7;
    const int srcRow = (n0 < F) ? (k0 + r) : (K + k0 + r);
    const int srcCol = (n0 < F) ? n0 : (n0 - F);
    float4 v = *(const float4*)(W + (size_t)srcRow * F + srcCol + cq * 4);
    tile[r][cq * 4 + 0] = v.x; tile[r][cq * 4 + 1] = v.y;
    tile[r][cq * 4 + 2] = v.z; tile[r][cq * 4 + 3] = v.w;
  }
  __syncthreads();
  {
    const int nl = t >> 3, kq = t & 7;
    ushort h[4], l[4];
#pragma unroll
    for (int i = 0; i < 4; ++i) split2(tile[kq * 4 + i][nl], h[i], l[i]);
    ushort4 vh = {h[0], h[1], h[2], h[3]};
    ushort4 vl = {l[0], l[1], l[2], l[3]};
    *(ushort4*)(WTH + (size_t)(n0 + nl) * K + k0 + kq * 4) = vh;
    *(ushort4*)(WTL + (size_t)(n0 + nl) * K + k0 + kq * 4) = vl;
  }
}

// ---------------- K6: layer epilogue ----------------
__global__ __launch_bounds__(256) void k_postlayer(const float* __restrict__ C, const float* __restrict__ adj,
                                                   const float* __restrict__ bias,
                                                   ushort* __restrict__ HH, ushort* __restrict__ HL, int F) {
  __shared__ float adjL[64 * 65];
  __shared__ float QL[64 * 66];
  const int f0 = blockIdx.x * 64;
  const int b = blockIdx.y;
  const int t = threadIdx.x;
  const int fc = t & 63, rg = t >> 6;
  const int twoF = 2 * F;
  for (int i = t; i < 4096; i += 256) {
    const int r = i >> 6, j = i & 63;
    adjL[r * 65 + j] = adj[(size_t)b * 4096 + i];
    QL[r * 66 + j] = C[(size_t)(b * 64 + r) * twoF + F + f0 + j];
  }
  __syncthreads();
  const float bv = bias[f0 + fc];
  for (int rr = 0; rr < 16; ++rr) {
    const int r = rg * 16 + rr;
    float s = 0.f;
#pragma unroll 8
    for (int j0 = 0; j0 < 64; ++j0) {
      const int j = (j0 + fc) & 63;
      s += adjL[r * 65 + j] * QL[j * 66 + fc];
    }
    const int row = b * 64 + r;
    float h = C[(size_t)row * twoF + f0 + fc] + s + bv;
    h = fmaxf(h, 0.f);
    ushort hh, hl;
    split2(h, hh, hl);
    HH[(size_t)row * F + f0 + fc] = hh;
    HL[(size_t)row * F + f0 + fc] = hl;
  }
}

// ---------------- K8: pred = prelu(CBUF + bc1) @ Wc2 + bc2 (fused classifier tail) ----------------
__global__ __launch_bounds__(256) void k_final2(const float* __restrict__ C, const float* __restrict__ bc1,
                                                const float* __restrict__ pre, const float* __restrict__ Wc2,
                                                const float* __restrict__ bc2, float* __restrict__ outp) {
  __shared__ float w[512];
  __shared__ float red[512];
  const int t = threadIdx.x;
  for (int i = t; i < 512; i += 256) w[i] = Wc2[i];
  __syncthreads();
  const int m = blockIdx.x * 64 + (t >> 2);
  const int p = t & 3;
  const float* h = C + (size_t)m * 256;
  float s0 = 0.f, s1 = 0.f;
  for (int k = p * 64; k < p * 64 + 64; ++k) {
    float hv = h[k] + bc1[k];
    hv = (hv > 0.f) ? hv : pre[k] * hv;
    s0 += hv * w[k * 2];
    s1 += hv * w[k * 2 + 1];
  }
  red[t * 2] = s0; red[t * 2 + 1] = s1;
  __syncthreads();
  if (p == 0) {
    for (int q = 1; q < 4; ++q) { s0 += red[(t + q) * 2]; s1 += red[(t + q) * 2 + 1]; }
    outp[m * 2 + 0] = s0 + bc2[0];
    outp[m * 2 + 1] = s1 + bc2[1];
  }
}

extern "C" void kernel_launch(void* const* d_in, const int* in_sizes, int n_in,
                              void* d_out, int out_size, void* d_ws, size_t ws_size,
                              hipStream_t stream) {
  const int*   indexes = (const int*)d_in[0];
  const float* F   = (const float*)d_in[1];
  const float* W1  = (const float*)d_in[4];
  const float* b1  = (const float*)d_in[5];
  const float* W2  = (const float*)d_in[6];
  const float* b2  = (const float*)d_in[7];
  const float* W3  = (const float*)d_in[8];
  const float* b3  = (const float*)d_in[9];
  const float* W4  = (const float*)d_in[10];
  const float* b4  = (const float*)d_in[11];
  const float* Wc1 = (const float*)d_in[12];
  const float* bc1 = (const float*)d_in[13];
  const float* pre = (const float*)d_in[14];
  const float* Wc2 = (const float*)d_in[15];
  const float* bc2 = (const float*)d_in[16];
  float* out = (float*)d_out;

  size_t off = 0;
  auto take = [&](size_t bytes) -> char* {
    char* q = (char*)d_ws + off;
    off += (bytes + 255) & ~(size_t)255;
    return q;
  };
  float* TOPV = (float*)take((size_t)NROWS * KSEL * 4);
  int*   TOPI = (int*)  take((size_t)NROWS * KSEL * 4);
  float* EXPS = (float*)take((size_t)NROWS * 4);
  float* ADJ  = (float*)take((size_t)64 * 64 * 64 * 4);
  char*  big  = (char*)d_ws + off;
  const size_t big_bytes = (ws_size > off) ? (ws_size - off) : 0;

  const size_t Mi = 1024 * 1024;
  const size_t Ki = 1024;
  const size_t splitBytes = (size_t)NROWS * DFEAT * 2;  // 32 Mi per split
  const size_t TSZ = (size_t)CHK * CHK;                 // floats per tile (16 Mi)

  auto enc = [](int ci, int cj, int ba, int bb, int dg) {
    return ci | (cj << 4) | (ba << 8) | (bb << 12) | (dg << 16);
  };

  if (big_bytes >= 224 * Mi) {
    // ---- 8-buffer batched path (R16 best-measured): 2 sim launches + 2 merged updates ----
    ushort* FH = (ushort*)big;
    ushort* FM = (ushort*)(big + splitBytes);
    ushort* FL = (ushort*)(big + 2 * splitBytes);
    float* BUFS = (float*)(big + 96 * Mi);   // 8 buffers of 16 Mi
    k_split<<<NROWS * DFEAT / 1024, 256, 0, stream>>>(F, FH, FM, FL);
    k_init_topk<<<NROWS * KSEL / 256, 256, 0, stream>>>(TOPV, TOPI);
    // S1: 4 diagonal tiles + pairs (0,1) and (2,3)
    k_sim_batch<<<dim3(16, 16, 6), 256, 0, stream>>>(FH, FM, FL, BUFS,
        enc(0,0,0,0,1), enc(1,1,1,1,1), enc(2,2,2,2,1), enc(3,3,3,3,1),
        enc(0,1,4,5,0), enc(2,3,6,7,0));
    // merged: row r <- (buf r, col r) + (buf 4+r, col [1,0,3,2][r])
    k_topk_upd2<<<dim3(CHK, 4), 256, 0, stream>>>(BUFS,
        0, 1, 2, 3,  0, 1, 2, 3,
        4, 5, 6, 7,  1, 0, 3, 2, TOPV, TOPI);
    // S2: pairs (0,2),(1,3),(0,3),(1,2)
    k_sim_batch<<<dim3(16, 16, 4), 256, 0, stream>>>(FH, FM, FL, BUFS,
        enc(0,2,0,1,0), enc(1,3,2,3,0), enc(0,3,4,5,0), enc(1,2,6,7,0), 0, 0);
    // merged: row0 <- (buf0,c2)+(buf4,c3); row1 <- (buf2,c3)+(buf6,c2);
    //         row2 <- (buf1,c0)+(buf7,c1); row3 <- (buf3,c1)+(buf5,c0)
    k_topk_upd2<<<dim3(CHK, 4), 256, 0, stream>>>(BUFS,
        0, 2, 1, 3,  2, 3, 0, 1,
        4, 6, 7, 5,  3, 2, 1, 0, TOPV, TOPI);
    k_exps<<<NROWS / 256, 256, 0, stream>>>(TOPV, EXPS);
  } else if (big_bytes >= 160 * Mi) {
    // ---- 4-buffer path (R11 schedule) ----
    ushort* FH = (ushort*)big;
    ushort* FM = (ushort*)(big + splitBytes);
    ushort* FL = (ushort*)(big + 2 * splitBytes);
    float* BUFS = (float*)(big + 96 * Mi);   // 4 buffers of 16 Mi
    k_split<<<NROWS * DFEAT / 1024, 256, 0, stream>>>(F, FH, FM, FL);
    k_init_topk<<<NROWS * KSEL / 256, 256, 0, stream>>>(TOPV, TOPI);
    k_sim_batch<<<dim3(16, 16, 4), 256, 0, stream>>>(FH, FM, FL, BUFS,
        enc(0,0,0,0,1), enc(1,1,1,1,1), enc(2,2,2,2,1), enc(3,3,3,3,1), 0, 0);
    k_topk_upd4<<<dim3(CHK, 4), 256, 0, stream>>>(BUFS, 0, 1, 2, 3, 0, 1, 2, 3, TOPV, TOPI);
    k_sim_batch<<<dim3(16, 16, 2), 256, 0, stream>>>(FH, FM, FL, BUFS,
        enc(0,1,0,1,0), enc(2,3,2,3,0), 0, 0, 0, 0);
    k_topk_upd4<<<dim3(CHK, 4), 256, 0, stream>>>(BUFS, 0, 1, 2, 3, 1, 0, 3, 2, TOPV, TOPI);
    k_sim_batch<<<dim3(16, 16, 2), 256, 0, stream>>>(FH, FM, FL, BUFS,
        enc(0,2,0,1,0), enc(1,3,2,3,0), 0, 0, 0, 0);
    k_topk_upd4<<<dim3(CHK, 4), 256, 0, stream>>>(BUFS, 0, 2, 1, 3, 2, 3, 0, 1, TOPV, TOPI);
    k_sim_batch<<<dim3(16, 16, 2), 256, 0, stream>>>(FH, FM, FL, BUFS,
        enc(0,3,0,1,0), enc(1,2,2,3,0), 0, 0, 0, 0);
    k_topk_upd4<<<dim3(CHK, 4), 256, 0, stream>>>(BUFS, 0, 2, 3, 1, 3, 2, 1, 0, TOPV, TOPI);
    k_exps<<<NROWS / 256, 256, 0, stream>>>(TOPV, EXPS);
  } else {
    int fchunk = 0;
    for (int c = 2048; c >= 512; c >>= 1) {
      if (3 * splitBytes + (size_t)c * NROWS * 4 <= big_bytes) { fchunk = c; break; }
    }
    if (fchunk == 0) {
      hipMemsetAsync(d_out, 0, (size_t)out_size * 4, stream);
      return;
    }
    ushort* FH = (ushort*)big;
    ushort* FM = (ushort*)(big + splitBytes);
    ushort* FL = (ushort*)(big + 2 * splitBytes);
    float* SIMC = (float*)(big + 3 * splitBytes);
    k_split<<<NROWS * DFEAT / 1024, 256, 0, stream>>>(F, FH, FM, FL);
    for (int r0 = 0; r0 < NROWS; r0 += fchunk) {
      k_simgemm_mfma<<<dim3(64, fchunk / 128), 256, 0, stream>>>(FH, FM, FL, SIMC, r0);
      k_topk<<<fchunk, 256, 0, stream>>>(SIMC, TOPV, TOPI, EXPS, r0);
    }
  }
  k_adj<<<64, 256, 0, stream>>>(indexes, TOPV, TOPI, EXPS, ADJ);

  // ---- phase B (aliases phase-A region; lifetime-checked) ----
  ushort* XH   = (ushort*)(big);
  ushort* XL   = (ushort*)(big + 16 * Mi);
  ushort* WT1H = (ushort*)(big + 32 * Mi);
  ushort* WT1L = (ushort*)(big + 40 * Mi);
  ushort* WT2H = (ushort*)(big + 48 * Mi);
  ushort* WT2L = (ushort*)(big + 50 * Mi);
  ushort* WT3H = (ushort*)(big + 52 * Mi);
  ushort* WT3L = (ushort*)(big + 52 * Mi + 512 * Ki);
  ushort* WT4H = (ushort*)(big + 53 * Mi);
  ushort* WT4L = (ushort*)(big + 53 * Mi + 256 * Ki);
  ushort* WTcH = (ushort*)(big + 53 * Mi + 512 * Ki);
  ushort* WTcL = (ushort*)(big + 53 * Mi + 640 * Ki);
  float*  CBUF = (float*)(big + 54 * Mi);
  ushort* H1H  = (ushort*)(big + 32 * Mi);
  ushort* H1L  = (ushort*)(big + 40 * Mi);
  ushort* H2H  = (ushort*)(big);
  ushort* H2L  = (ushort*)(big + 4 * Mi);
  ushort* H3H  = (ushort*)(big + 8 * Mi);
  ushort* H3L  = (ushort*)(big + 10 * Mi);
  ushort* H4H  = (ushort*)(big + 12 * Mi);
  ushort* H4L  = (ushort*)(big + 14 * Mi);

  k_wsplitT<<<dim3(2048 / 32, 2048 / 32), 256, 0, stream>>>(W1, WT1H, WT1L, 2048, 1024);
  k_wsplitT<<<dim3(1024 / 32, 1024 / 32), 256, 0, stream>>>(W2, WT2H, WT2L, 1024, 512);
  k_wsplitT<<<dim3(512 / 32, 512 / 32), 256, 0, stream>>>(W3, WT3H, WT3L, 512, 256);
  k_wsplitT<<<dim3(256 / 32, 512 / 32), 256, 0, stream>>>(W4, WT4H, WT4L, 256, 256);
  k_wsplitT<<<dim3(256 / 32, 256 / 32), 256, 0, stream>>>(Wc1, WTcH, WTcL, 256, 256);

  k_xs_split<<<dim3(64, 64), 256, 0, stream>>>(indexes, TOPI, F, XH, XL);

  k_gemm3<<<dim3(16, 32), 256, 0, stream>>>(XH, XL, WT1H, WT1L, CBUF, 2048, 2048);
  k_postlayer<<<dim3(16, 64), 256, 0, stream>>>(CBUF, ADJ, b1, H1H, H1L, 1024);
  k_gemm3<<<dim3(8, 32), 256, 0, stream>>>(H1H, H1L, WT2H, WT2L, CBUF, 1024, 1024);
  k_postlayer<<<dim3(8, 64), 256, 0, stream>>>(CBUF, ADJ, b2, H2H, H2L, 512);
  k_gemm3<<<dim3(4, 32), 256, 0, stream>>>(H2H, H2L, WT3H, WT3L, CBUF, 512, 512);
  k_postlayer<<<dim3(4, 64), 256, 0, stream>>>(CBUF, ADJ, b3, H3H, H3L, 256);
  k_gemm3<<<dim3(4, 32), 256, 0, stream>>>(H3H, H3L, WT4H, WT4L, CBUF, 256, 512);
  k_postlayer<<<dim3(4, 64), 256, 0, stream>>>(CBUF, ADJ, b4, H4H, H4L, 256);
  k_gemm3<<<dim3(2, 32), 256, 0, stream>>>(H4H, H4L, WTcH, WTcL, CBUF, 256, 256);
  k_final2<<<64, 256, 0, stream>>>(CBUF, bc1, pre, Wc2, bc2, out);
}